// Round 8
// baseline (33.932 us; speedup 1.0000x reference)
//
#include <hip/hip_runtime.h>
#include <cstdint>
#include <math.h>

#define N_FRAMES 16777216          // 2^24
#define MAX_BEATS (N_FRAMES / 8)   // 2097152
#define CHUNK 4096
#define NTHREADS 256
#define NCHUNK (N_FRAMES / CHUNK)  // 4096 chunks (k_count blocks)
#define NWAVES (NCHUNK * 4)        // 16384 wave-level counts
#define NBLK (NCHUNK / 4)          // 1024 emit blocks (4 waves, 1 chunk each)
#define TOTAL_MASKS ((size_t)NCHUNK * 64)

typedef unsigned long long u64;
typedef unsigned int u32;
typedef unsigned short u16;

__device__ __forceinline__ float max3f(float a, float b, float c) {
  return fmaxf(fmaxf(a, b), c);
}

// k_count: pure wave-level. 16 elems/thread register stencil; per-thread u16 mask
// store (same byte layout as u64 masks); locally-computed carry bit; per-wave counts.
// No LDS, no __syncthreads.
__global__ __launch_bounds__(NTHREADS) void k_count(const float* __restrict__ x,
                                                    int* __restrict__ countsW,
                                                    u16* __restrict__ masks16) {
  const int b = blockIdx.x;
  const int t = threadIdx.x;
  const int gbase = b * CHUNK + t * 16;

  // v[k] = x[gbase - 4 + k], k in [0,24)
  float v[24];
  if (gbase - 4 >= 0 && gbase + 20 <= N_FRAMES) {
    const float4* p = reinterpret_cast<const float4*>(x + gbase - 4);
#pragma unroll
    for (int k = 0; k < 6; ++k) {
      const float4 f = p[k];
      v[4 * k + 0] = f.x; v[4 * k + 1] = f.y; v[4 * k + 2] = f.z; v[4 * k + 3] = f.w;
    }
  } else {
#pragma unroll
    for (int k = 0; k < 24; ++k) {
      const int gi = gbase - 4 + k;
      v[k] = (gi >= 0 && gi < N_FRAMES) ? x[gi] : -INFINITY;
    }
  }

  // trio maxes: Lt[i] = max(v[i..i+2]); window(e) = max(Lt[e+1], Lt[e+5])
  float Lt[21];
#pragma unroll
  for (int i = 0; i < 21; ++i) Lt[i] = max3f(v[i], v[i + 1], v[i + 2]);

  u32 pm = 0;
#pragma unroll
  for (int e = 0; e < 16; ++e) {
    const float c = v[e + 4];
    const float m = fmaxf(Lt[e + 1], Lt[e + 5]);
    if (c > 0.0f && c >= m) pm |= (1u << e);
  }
  masks16[b * NTHREADS + t] = (u16)pm;

  // carry = peak at gbase-1, computed from this thread's own window (bit-identical
  // to neighbor's bit15: c=v[3], window trios Lt[0], Lt[4])
  const float cm1 = v[3];
  const u32 carry = (cm1 > 0.0f && cm1 >= fmaxf(Lt[0], Lt[4])) ? 1u : 0u;

  int cnt = __popc(pm & ~((pm << 1) | carry));
#pragma unroll
  for (int off = 32; off; off >>= 1) cnt += __shfl_down(cnt, off, 64);
  if ((t & 63) == 0) countsW[b * 4 + (t >> 6)] = cnt;
}

// k_emit: 4 waves/block, wave wv owns chunk blockIdx.x*4+wv. Inlines the global
// scan over per-wave counts (64 KB, L2-hot, int4 loads). Emits sections + -1 tail.
__global__ __launch_bounds__(NTHREADS) void k_emit(const u64* __restrict__ masks,
                                                   const int* __restrict__ countsW,
                                                   float* __restrict__ out) {
  __shared__ int s_wtot[4];
  __shared__ int s_texcl[NTHREADS];
  __shared__ int s_off[4];
  __shared__ int s_total;
  const int t = threadIdx.x, lane = t & 63, wv = t >> 6;

  // global scan recompute: thread t owns countsW[64t .. 64t+64), via 16 int4 loads
  int s = 0;
  {
    const int4* c4 = reinterpret_cast<const int4*>(countsW + t * 64);
#pragma unroll
    for (int e = 0; e < 16; ++e) {
      const int4 q = c4[e];
      s += q.x + q.y + q.z + q.w;
    }
  }
  int incl = s;
#pragma unroll
  for (int off = 1; off < 64; off <<= 1) {
    const int vv = __shfl_up(incl, off, 64);
    if (lane >= off) incl += vv;
  }
  s_texcl[t] = incl - s;
  if (lane == 63) s_wtot[wv] = incl;
  __syncthreads();
  if (t == 0) s_total = s_wtot[0] + s_wtot[1] + s_wtot[2] + s_wtot[3];
  if (t < 4) {   // offset of chunk blockIdx.x*4 + t  (= countsW prefix up to 4*target)
    const int target = blockIdx.x * 4 + t;
    const int w0 = target * 4;           // first wave-count index of this chunk
    const int j = w0 >> 6, r = w0 & 63;  // owning scan-thread, remainder
    int wb = 0;
    for (int ww = 0; ww < (j >> 6); ++ww) wb += s_wtot[ww];
    int pfx = wb + s_texcl[j];
    for (int e = 0; e < r; ++e) pfx += countsW[j * 64 + e];
    s_off[t] = pfx;
  }
  __syncthreads();

  const int b = blockIdx.x * 4 + wv;
  const size_t mi = ((size_t)b << 6) + lane;
  const u64 m = masks[mi];
  const u32 myb63 = (u32)(m >> 63);
  u32 prevb = __shfl_up(myb63, 1, 64);
  if (lane == 0) prevb = (b == 0) ? 0u : (u32)(masks[mi - 1] >> 63);
  u64 sm = m & ~((m << 1) | (u64)prevb);
  const int cnt = __popcll(sm);

  int incl2 = cnt;
#pragma unroll
  for (int off = 1; off < 64; off <<= 1) {
    const int vv = __shfl_up(incl2, off, 64);
    if (lane >= off) incl2 += vv;
  }
  int sid = s_off[wv] + incl2 - cnt;

  if (s_off[wv] < MAX_BEATS) {   // chunks entirely past the cutoff emit nothing
    const int gbase = b * CHUNK + lane * 64;
    while (sm) {
      const int sb = __builtin_ctzll(sm);
      sm &= sm - 1;
      const int i0 = gbase + sb;
      const u64 above = m >> sb;           // bit 0 = this peak
      const int len = (~above == 0ull) ? (64 - sb) : __builtin_ctzll(~above);
      int end = i0 + len - 1;
      if (sb + len == 64) {                // run continues into next mask (ties; rare)
        size_t idx = mi + 1;
        while (idx < TOTAL_MASKS) {
          const u64 mm = masks[idx];
          if (~mm == 0ull) { end += 64; ++idx; }
          else { end += __builtin_ctzll(~mm); break; }
        }
      }
      if (sid < MAX_BEATS)
        out[sid] = (float)(((double)i0 + (double)end) * 0.5);
      ++sid;
    }
  }

  // -1 tail fill: this block covers out[blockIdx*2048 .. +2048)
  const int lo = blockIdx.x * (MAX_BEATS / NBLK);
  const int hi = lo + (MAX_BEATS / NBLK);
  for (int i = max(lo, s_total) + t; i < hi; i += NTHREADS)
    out[i] = -1.0f;
}

extern "C" void kernel_launch(void* const* d_in, const int* in_sizes, int n_in,
                              void* d_out, int out_size, void* d_ws, size_t ws_size,
                              hipStream_t stream) {
  const float* x = (const float*)d_in[0];
  float* out = (float*)d_out;

  u16* masks16 = (u16*)d_ws;                           // 2 MiB (u64-view identical)
  int* countsW = (int*)((char*)d_ws + TOTAL_MASKS * 8);  // 64 KiB

  k_count<<<NCHUNK, NTHREADS, 0, stream>>>(x, countsW, masks16);
  k_emit<<<NBLK, NTHREADS, 0, stream>>>((const u64*)masks16, countsW, out);
}